// Round 4
// baseline (940.744 us; speedup 1.0000x reference)
//
#include <hip/hip_runtime.h>
#include <hip/hip_bf16.h>
#include <stdint.h>
#include <math.h>

#define NTOK  2048
#define HDIM  1024
#define FDIM  768
#define NEXP  32
#define TOPK  8
#define CAP   1024
#define LDA   72      // padded A-row stride in shorts (144B): 2-way bank alias only (free)

typedef __attribute__((ext_vector_type(8))) short short8;
typedef __attribute__((ext_vector_type(4))) float f32x4;

__device__ __forceinline__ short f2bf(float f) {
  union { float f; uint32_t u; } c; c.f = f;
  uint32_t u = c.u;
  u += 0x7fffu + ((u >> 16) & 1u);   // RNE
  return (short)(u >> 16);
}

__device__ __forceinline__ short8 pack8(float4 a, float4 b) {
  short8 r;
  r[0] = f2bf(a.x); r[1] = f2bf(a.y); r[2] = f2bf(a.z); r[3] = f2bf(a.w);
  r[4] = f2bf(b.x); r[5] = f2bf(b.y); r[6] = f2bf(b.z); r[7] = f2bf(b.w);
  return r;
}

// packed fp32->bf16 (round-half-up): dst = bf(a) | bf(b)<<16
__device__ __forceinline__ uint32_t pkbf(uint32_t a, uint32_t b) {
  return __builtin_amdgcn_perm(b + 0x8000u, a + 0x8000u, 0x07060302u);
}

// read 8 consecutive fp32 from LDS -> bf16 MFMA fragment (validated R2 call-1)
__device__ __forceinline__ short8 cvt_frag(const float* p) {
  uint4 a = *(const uint4*)p;
  uint4 b = *(const uint4*)(p + 4);
  union { uint32_t u[4]; short8 s; } r;
  r.u[0] = pkbf(a.x, a.y);
  r.u[1] = pkbf(a.z, a.w);
  r.u[2] = pkbf(b.x, b.y);
  r.u[3] = pkbf(b.z, b.w);
  return r.s;
}

// async global->LDS 16B/lane; ONLY used on pristine d_in weights (no RAW hazard)
__device__ __forceinline__ void gld16(void* lds, const void* g) {
  __builtin_amdgcn_global_load_lds((const __attribute__((address_space(1))) void*)g,
                                   (__attribute__((address_space(3))) void*)lds, 16, 0, 0);
}

// ---------------- router ----------------
__global__ __launch_bounds__(256) void router_kern(
    const float* __restrict__ x, const float* __restrict__ gw,
    int* __restrict__ cnt, int* __restrict__ slot_tok,
    float* __restrict__ slot_w, short* __restrict__ xb) {
  const int n0 = blockIdx.x * 4;
  const int t  = threadIdx.x;
  __shared__ float ls[4][32];

  const int e = t >> 3;
  const int j = t & 7;
  float acc[4] = {0.f, 0.f, 0.f, 0.f};
  const float4* gw4 = (const float4*)(gw + (size_t)e * HDIM);
  const float4* x4  = (const float4*)(x + (size_t)n0 * HDIM);
  for (int i = 0; i < 32; ++i) {
    const int c = j + 8 * i;
    const float4 g = gw4[c];
#pragma unroll
    for (int tok = 0; tok < 4; ++tok) {
      const float4 xv = x4[tok * 256 + c];
      acc[tok] += g.x * xv.x + g.y * xv.y + g.z * xv.z + g.w * xv.w;
    }
  }
#pragma unroll
  for (int tok = 0; tok < 4; ++tok) {
    float v = acc[tok];
    v += __shfl_xor(v, 1); v += __shfl_xor(v, 2); v += __shfl_xor(v, 4);
    if (j == 0) ls[tok][e] = v;
  }
  __syncthreads();

  if (t < 4) {
    const int n = n0 + t;
    float lv[32];
#pragma unroll
    for (int i = 0; i < 32; ++i) lv[i] = ls[t][i];
    int   idx[TOPK];
    float val[TOPK];
    for (int kk = 0; kk < TOPK; ++kk) {
      float best = -INFINITY; int bi = 0;
      for (int i = 0; i < 32; ++i)
        if (lv[i] > best) { best = lv[i]; bi = i; }
      val[kk] = best; idx[kk] = bi; lv[bi] = -INFINITY;
    }
    const float m = val[0];
    float w[TOPK]; float wsum = 0.f;
    for (int kk = 0; kk < TOPK; ++kk) { w[kk] = __expf(val[kk] - m); wsum += w[kk]; }
    const float inv = 1.f / wsum;
    for (int kk = 0; kk < TOPK; ++kk) {
      const int ee = idx[kk];
      const int pos = atomicAdd(&cnt[ee], 1);
      if (pos < CAP) {
        slot_tok[ee * CAP + pos] = n * TOPK + kk;
        slot_w[ee * CAP + pos]   = w[kk] * inv;
      }
    }
  }

  const size_t base = (size_t)n0 * HDIM + (size_t)t * 16;
  const float4* xp = (const float4*)(x + base);
  short8* xo = (short8*)(xb + base);
  xo[0] = pack8(xp[0], xp[1]);
  xo[1] = pack8(xp[2], xp[3]);
}

// ---------------- GEMM1: h = silu(x@Wg^T) * (x@Wu^T) ----------------
// 128 tokens x 64 f, BK=64. A: explicit bf16 staging (device-written xb).
// B: global_load_lds fp32 (pristine weights), convert at fragment read.
__global__ __launch_bounds__(256) void gemm1_kern(
    const short* __restrict__ xb, const float* __restrict__ gup,
    const int* __restrict__ cnt, const int* __restrict__ slot_tok,
    short* __restrict__ hbuf) {
  const int e = blockIdx.z;
  const int mcnt = min(cnt[e], CAP);
  const int r0 = blockIdx.x * 128;    // token tile FASTEST -> same-B blocks adjacent
  if (r0 >= mcnt) return;
  const int f0 = blockIdx.y * 64;

  __shared__ short As[128 * LDA];     // 18.4KB bf16 tokens
  __shared__ float Bsf[128 * 64];     // 32KB fp32 weights, rows: g f0..f0+63 | u f0..f0+63
  __shared__ int tokL[128];

  const int t = threadIdx.x;
  if (t < 128) {
    int s = (r0 + t < mcnt) ? slot_tok[e * CAP + r0 + t] : 0;
    tokL[t] = s >> 3;
  }
  __syncthreads();

  const int wave = t >> 6, lane = t & 63;

  // A staging: 2 threads/row, 32 shorts each (R3-validated)
  const int sr = t >> 1;
  const int sk = (t & 1) * 32;
  const short* aptr = xb + (size_t)tokL[sr] * HDIM + sk;
  short* adst = &As[sr * LDA + sk];

  // B DMA: 8 issues/thread; issue i covers LDS rows 32w+4i..+3 (256B fp32 rows)
  const float* srcB[8]; float* dstB[8];
#pragma unroll
  for (int i = 0; i < 8; ++i) {
    const int lr = 32 * wave + 4 * i + (lane >> 4);
    const int frow = (lr < 64) ? (f0 + lr) : (FDIM + f0 + lr - 64);
    srcB[i] = gup + ((size_t)e * (2 * FDIM) + frow) * HDIM + (lane & 15) * 4;
    dstB[i] = &Bsf[lr * 64 + (lane & 15) * 4];
  }

  const int wm = wave & 1, wn = wave >> 1;
  const int lrow = lane & 15, q8 = (lane >> 4) * 8;

  f32x4 accg[4][2], accu[4][2];
#pragma unroll
  for (int a = 0; a < 4; ++a)
#pragma unroll
    for (int b = 0; b < 2; ++b) {
      accg[a][b] = (f32x4){0.f, 0.f, 0.f, 0.f};
      accu[a][b] = (f32x4){0.f, 0.f, 0.f, 0.f};
    }

  uint4 aR[4];
#pragma unroll
  for (int i = 0; i < 4; ++i) aR[i] = *(const uint4*)(aptr + 8 * i);

  for (int kb = 0; kb < HDIM; kb += 64) {
    __syncthreads();   // previous iteration's LDS reads done
#pragma unroll
    for (int i = 0; i < 4; ++i) *(uint4*)(adst + 8 * i) = aR[i];
#pragma unroll
    for (int i = 0; i < 8; ++i) gld16(dstB[i], srcB[i] + kb);
    __syncthreads();   // drains B DMA + A writes

    if (kb + 64 < HDIM) {            // A prefetch overlaps compute
#pragma unroll
      for (int i = 0; i < 4; ++i) aR[i] = *(const uint4*)(aptr + kb + 64 + 8 * i);
    }

#pragma unroll
    for (int ks = 0; ks < 64; ks += 32) {
      short8 af[4], bg[2], bu[2];
#pragma unroll
      for (int mt = 0; mt < 4; ++mt)
        af[mt] = *(const short8*)&As[(64 * wm + 16 * mt + lrow) * LDA + ks + q8];
#pragma unroll
      for (int nt = 0; nt < 2; ++nt) {
        bg[nt] = cvt_frag(&Bsf[(32 * wn + 16 * nt + lrow) * 64 + ks + q8]);
        bu[nt] = cvt_frag(&Bsf[(64 + 32 * wn + 16 * nt + lrow) * 64 + ks + q8]);
      }
#pragma unroll
      for (int mt = 0; mt < 4; ++mt)
#pragma unroll
        for (int nt = 0; nt < 2; ++nt) {
          accg[mt][nt] = __builtin_amdgcn_mfma_f32_16x16x32_bf16(af[mt], bg[nt], accg[mt][nt], 0, 0, 0);
          accu[mt][nt] = __builtin_amdgcn_mfma_f32_16x16x32_bf16(af[mt], bu[nt], accu[mt][nt], 0, 0, 0);
        }
    }
  }

  // epilogue: silu(g)*u -> bf16 hbuf[e][pos][f]
#pragma unroll
  for (int mt = 0; mt < 4; ++mt)
#pragma unroll
    for (int nt = 0; nt < 2; ++nt)
#pragma unroll
      for (int r = 0; r < 4; ++r) {
        const int pos = r0 + 64 * wm + 16 * mt + (lane >> 4) * 4 + r;
        if (pos < mcnt) {
          const int f = f0 + 32 * wn + 16 * nt + lrow;
          const float g = accg[mt][nt][r];
          const float u = accu[mt][nt][r];
          const float hv = (g / (1.f + __expf(-g))) * u;
          hbuf[((size_t)e * CAP + pos) * FDIM + f] = f2bf(hv);
        }
      }
}

// ---------------- GEMM2: slot_out[s] = w_s * (h @ Wd^T) ----------------
// 128 tokens x 128 H, BK=64. A: explicit (device-written hbuf). B: gld16 fp32.
__global__ __launch_bounds__(256) void gemm2_kern(
    const short* __restrict__ hbuf, const float* __restrict__ dwn,
    const int* __restrict__ cnt, const int* __restrict__ slot_tok,
    const float* __restrict__ slot_w, float* __restrict__ slot_out) {
  const int e = blockIdx.z;
  const int mcnt = min(cnt[e], CAP);
  const int r0 = blockIdx.x * 128;    // token tile fastest
  if (r0 >= mcnt) return;
  const int n0 = blockIdx.y * 128;

  __shared__ short As[128 * LDA];
  __shared__ float Bsf[128 * 64];
  __shared__ int   tokL[128];
  __shared__ float wL[128];

  const int t = threadIdx.x;
  if (t < 128) {
    const bool v = (r0 + t) < mcnt;
    tokL[t] = v ? slot_tok[e * CAP + r0 + t] : 0;
    wL[t]   = v ? slot_w[e * CAP + r0 + t] : 0.f;
  }
  __syncthreads();

  const int wave = t >> 6, lane = t & 63;

  const int sr = t >> 1;
  const int sk = (t & 1) * 32;
  const short* aptr = hbuf + ((size_t)e * CAP + r0 + sr) * FDIM + sk;
  short* adst = &As[sr * LDA + sk];

  const float* srcB[8]; float* dstB[8];
#pragma unroll
  for (int i = 0; i < 8; ++i) {
    const int lr = 32 * wave + 4 * i + (lane >> 4);
    srcB[i] = dwn + ((size_t)e * HDIM + n0 + lr) * FDIM + (lane & 15) * 4;
    dstB[i] = &Bsf[lr * 64 + (lane & 15) * 4];
  }

  const int wm = wave & 1, wn = wave >> 1;
  const int lrow = lane & 15, q8 = (lane >> 4) * 8;

  f32x4 acc[4][4];
#pragma unroll
  for (int a = 0; a < 4; ++a)
#pragma unroll
    for (int b = 0; b < 4; ++b) acc[a][b] = (f32x4){0.f, 0.f, 0.f, 0.f};

  uint4 aR[4];
#pragma unroll
  for (int i = 0; i < 4; ++i) aR[i] = *(const uint4*)(aptr + 8 * i);

  for (int kb = 0; kb < FDIM; kb += 64) {
    __syncthreads();
#pragma unroll
    for (int i = 0; i < 4; ++i) *(uint4*)(adst + 8 * i) = aR[i];
#pragma unroll
    for (int i = 0; i < 8; ++i) gld16(dstB[i], srcB[i] + kb);
    __syncthreads();

    if (kb + 64 < FDIM) {
#pragma unroll
      for (int i = 0; i < 4; ++i) aR[i] = *(const uint4*)(aptr + kb + 64 + 8 * i);
    }

#pragma unroll
    for (int ks = 0; ks < 64; ks += 32) {
      short8 af[4], bf[4];
#pragma unroll
      for (int mt = 0; mt < 4; ++mt)
        af[mt] = *(const short8*)&As[(64 * wm + 16 * mt + lrow) * LDA + ks + q8];
#pragma unroll
      for (int nt = 0; nt < 4; ++nt)
        bf[nt] = cvt_frag(&Bsf[(64 * wn + 16 * nt + lrow) * 64 + ks + q8]);
#pragma unroll
      for (int mt = 0; mt < 4; ++mt)
#pragma unroll
        for (int nt = 0; nt < 4; ++nt)
          acc[mt][nt] = __builtin_amdgcn_mfma_f32_16x16x32_bf16(af[mt], bf[nt], acc[mt][nt], 0, 0, 0);
    }
  }

#pragma unroll
  for (int mt = 0; mt < 4; ++mt)
#pragma unroll
    for (int nt = 0; nt < 4; ++nt)
#pragma unroll
      for (int r = 0; r < 4; ++r) {
        const int prow = 64 * wm + 16 * mt + (lane >> 4) * 4 + r;
        if (r0 + prow < mcnt) {
          const int s = tokL[prow];
          const float w = wL[prow];
          const int col = n0 + 64 * wn + 16 * nt + lrow;
          slot_out[(size_t)s * HDIM + col] = w * acc[mt][nt][r];
        }
      }
}

// ---------------- gather ----------------
__global__ __launch_bounds__(256) void gather_kern(
    const float* __restrict__ so, float* __restrict__ out) {
  const int n = blockIdx.x;
  const int c = threadIdx.x * 4;
  float4 a = make_float4(0.f, 0.f, 0.f, 0.f);
#pragma unroll
  for (int k = 0; k < TOPK; ++k) {
    const float4 v = *(const float4*)&so[((size_t)(n * TOPK + k)) * HDIM + c];
    a.x += v.x; a.y += v.y; a.z += v.z; a.w += v.w;
  }
  *(float4*)&out[(size_t)n * HDIM + c] = a;
}

extern "C" void kernel_launch(void* const* d_in, const int* in_sizes, int n_in,
                              void* d_out, int out_size, void* d_ws, size_t ws_size,
                              hipStream_t stream) {
  const float* x   = (const float*)d_in[0];
  const float* gw  = (const float*)d_in[1];
  const float* gup = (const float*)d_in[2];
  const float* dwn = (const float*)d_in[3];
  float* out = (float*)d_out;

  char* ws = (char*)d_ws;
  int*   cnt      = (int*)(ws + 0);
  int*   slot_tok = (int*)(ws + 1024);
  float* slot_w   = (float*)(ws + 1024 + 131072);
  short* xb       = (short*)(ws + 524288);
  short* hbuf     = (short*)(ws + 524288 + 4194304);
  float* slot_out = (float*)(ws + 524288 + 4194304 + 50331648);

  hipMemsetAsync(cnt, 0, 1024, stream);
  router_kern<<<NTOK / 4, 256, 0, stream>>>(x, gw, cnt, slot_tok, slot_w, xb);
  gemm1_kern<<<dim3(CAP / 128, FDIM / 64, NEXP), 256, 0, stream>>>(xb, gup, cnt, slot_tok, hbuf);
  gemm2_kern<<<dim3(CAP / 128, HDIM / 128, NEXP), 256, 0, stream>>>(hbuf, dwn, cnt, slot_tok, slot_w, slot_out);
  gather_kern<<<NTOK, 256, 0, stream>>>(slot_out, out);
}